// Round 7
// baseline (65.675 us; speedup 1.0000x reference)
//
#include <hip/hip_runtime.h>
#include <cstdint>
#include <cstddef>

// Dims (fixed by the reference)
#define R_   16
#define NH_  8
#define D_   32
#define C_   256
#define B_   16
#define XY_  1024      // 32*32
#define RH_  128       // R_*NH_
#define KD_  4096      // R_*NH_*D_
#define NT   64        // positions per block (lane = position)

#define LD4(p) (*reinterpret_cast<const float4*>(p))

// ---------------------------------------------------------------------------
// Precompute, 2x parallel (256 blocks): bid = rh*2 + half.
//   half 0: k[d] = Wk[r,h*D+d,:]·rims[r,:]+bk  ->  WLt[c][rh], c0[rh]
//   half 1: v[d] = Wv[...]·rims+bv             ->  Uo[rh][c]
// ---------------------------------------------------------------------------
__global__ __launch_bounds__(256)
void rims_precompute(const float* __restrict__ rims,
                     const float* __restrict__ Wk,
                     const float* __restrict__ bk,
                     const float* __restrict__ Wv,
                     const float* __restrict__ bv,
                     const float* __restrict__ Wq,
                     const float* __restrict__ bq,
                     const float* __restrict__ Wm,
                     float* __restrict__ WLt,
                     float* __restrict__ Uo,
                     float* __restrict__ c0o)
{
    const int bid  = blockIdx.x;       // 0..255
    const int rh   = bid >> 1;         // 0..127
    const int half = bid & 1;          // 0: k/WLt, 1: v/Uo
    const int r    = rh >> 3;
    const int h    = rh & 7;
    const int tid  = threadIdx.x;

    __shared__ float kv[D_];

    {
        const int d    = tid >> 3;     // 0..31
        const int part = tid & 7;      // 0..7
        const float* Wsrc = (half ? Wv : Wk)
                          + ((size_t)r * 256 + h * D_ + d) * C_ + part * 32;
        const float* rr   = rims + r * C_ + part * 32;
        float a0 = 0.f, a1 = 0.f, a2 = 0.f, a3 = 0.f;
        #pragma unroll
        for (int j = 0; j < 8; ++j) {
            const float4 wv4 = LD4(Wsrc + j * 4);
            const float4 xv4 = LD4(rr + j * 4);
            a0 = fmaf(wv4.x, xv4.x, a0); a1 = fmaf(wv4.y, xv4.y, a1);
            a2 = fmaf(wv4.z, xv4.z, a2); a3 = fmaf(wv4.w, xv4.w, a3);
        }
        float acc = (a0 + a1) + (a2 + a3);
        acc += __shfl_xor(acc, 1);
        acc += __shfl_xor(acc, 2);
        acc += __shfl_xor(acc, 4);
        if (part == 0)
            kv[d] = acc + (half ? bv : bk)[r * 256 + h * D_ + d];
    }
    __syncthreads();

    const int c = tid;                 // 0..255
    if (half == 0) {
        float wl = 0.f;
        const float* wqp = Wq + (size_t)rh * D_ * C_ + c;
        #pragma unroll
        for (int d = 0; d < D_; ++d)
            wl = fmaf(kv[d], wqp[(size_t)d * C_], wl);
        WLt[c * RH_ + rh] = wl;        // [c][rh]

        if (tid < D_) {
            float s = kv[tid] * bq[rh * D_ + tid];
            s += __shfl_xor(s, 1);  s += __shfl_xor(s, 2);  s += __shfl_xor(s, 4);
            s += __shfl_xor(s, 8);  s += __shfl_xor(s, 16);
            if (tid == 0) c0o[rh] = s;
        }
    } else {
        float uu = 0.f;
        const float* wmp = Wm + (size_t)c * KD_ + rh * D_;
        #pragma unroll
        for (int d4 = 0; d4 < D_; d4 += 4) {
            const float4 m4 = LD4(wmp + d4);
            uu = fmaf(kv[d4 + 0], m4.x, uu);
            uu = fmaf(kv[d4 + 1], m4.y, uu);
            uu = fmaf(kv[d4 + 2], m4.z, uu);
            uu = fmaf(kv[d4 + 3], m4.w, uu);
        }
        Uo[rh * C_ + c] = uu;          // [rh][c]
    }
}

// ---------------------------------------------------------------------------
// Fused main: 256 blocks x 1024 threads (16 waves). lane = position.
//   GEMM1 split-K: waves 0-7 own all 128 rh rows for k in [0,128) -> Ls(+c0);
//                  waves 8-15 same rows for k in [128,256)        -> Lp.
//   Per wave: 16 rh rows -> 16 FMA per ds_read_b32 (LDS pipe 2x headroom).
//   Weights: 64 B/step contiguous, depth-2 float4 register prefetch pipeline.
//   softmax over r per (h,p) folds the split-K reduce: vals = Ls + Lp.
//   GEMM2: wave w owns 16 c rows, K=128, same prefetch structure.
// LDS = 128 KB (Zs 64 + Ls 32 + Lp 32); all LDS lane-stride-1 (conflict-free).
// ---------------------------------------------------------------------------
__global__ __launch_bounds__(1024, 4)
void rims_main(const float* __restrict__ z,
               const float* __restrict__ WLt,
               const float* __restrict__ Uo,
               const float* __restrict__ c0v,
               const float* __restrict__ bm,
               float* __restrict__ out)
{
    __shared__ __align__(16) float Zs[C_ * NT];    // 64 KB [c][p]
    __shared__ __align__(16) float Ls[RH_ * NT];   // 32 KB [rh][p] (K-half 0, then attn)
    __shared__ __align__(16) float Lp[RH_ * NT];   // 32 KB [rh][p] (K-half 1)

    const int tid  = threadIdx.x;
    const int lane = tid & 63;
    const int w    = __builtin_amdgcn_readfirstlane(tid >> 6);  // 0..15
    const int b    = blockIdx.x >> 4;
    const int xy0  = (blockIdx.x & 15) * NT;
    const float* zb = z + ((size_t)b * C_) * XY_ + xy0;

    // ---- stage z tile: 4 float4/thread, coalesced 256 B rows ----
    {
        const int srow = tid >> 4;          // 0..63
        const int scol = (tid & 15) << 2;   // 0,4,..60
        const float4 z0 = LD4(zb + (size_t)(srow      ) * XY_ + scol);
        const float4 z1 = LD4(zb + (size_t)(srow +  64) * XY_ + scol);
        const float4 z2 = LD4(zb + (size_t)(srow + 128) * XY_ + scol);
        const float4 z3 = LD4(zb + (size_t)(srow + 192) * XY_ + scol);
        *reinterpret_cast<float4*>(&Zs[(srow      ) * NT + scol]) = z0;
        *reinterpret_cast<float4*>(&Zs[(srow +  64) * NT + scol]) = z1;
        *reinterpret_cast<float4*>(&Zs[(srow + 128) * NT + scol]) = z2;
        *reinterpret_cast<float4*>(&Zs[(srow + 192) * NT + scol]) = z3;
    }
    __syncthreads();

    // ---- GEMM1 (split-K): wave w -> rows [(w&7)*16, +16), K-half w>>3 ----
    {
        const int hk  = w >> 3;                       // 0 or 1
        const int rh0 = (w & 7) << 4;                 // 0..112
        const float* wp = WLt + (size_t)(hk * 128) * RH_ + rh0;
        const float* zp = &Zs[(hk * 128) * NT + lane];

        float4 a0 = LD4(wp + 0),        a1 = LD4(wp + 4),
               a2 = LD4(wp + 8),        a3 = LD4(wp + 12);
        float4 b0 = LD4(wp + RH_ + 0),  b1 = LD4(wp + RH_ + 4),
               b2 = LD4(wp + RH_ + 8),  b3 = LD4(wp + RH_ + 12);

        float acc[16];
        #pragma unroll
        for (int j = 0; j < 16; ++j) acc[j] = 0.f;

        #pragma unroll 2
        for (int c = 0; c < 128; ++c) {
            const float zv = zp[c * NT];
            const int cc = (c + 2 < 128) ? c + 2 : 127;       // uniform, cheap
            const float4 n0 = LD4(wp + (size_t)cc * RH_ + 0);
            const float4 n1 = LD4(wp + (size_t)cc * RH_ + 4);
            const float4 n2 = LD4(wp + (size_t)cc * RH_ + 8);
            const float4 n3 = LD4(wp + (size_t)cc * RH_ + 12);

            acc[ 0] = fmaf(a0.x, zv, acc[ 0]);
            acc[ 1] = fmaf(a0.y, zv, acc[ 1]);
            acc[ 2] = fmaf(a0.z, zv, acc[ 2]);
            acc[ 3] = fmaf(a0.w, zv, acc[ 3]);
            acc[ 4] = fmaf(a1.x, zv, acc[ 4]);
            acc[ 5] = fmaf(a1.y, zv, acc[ 5]);
            acc[ 6] = fmaf(a1.z, zv, acc[ 6]);
            acc[ 7] = fmaf(a1.w, zv, acc[ 7]);
            acc[ 8] = fmaf(a2.x, zv, acc[ 8]);
            acc[ 9] = fmaf(a2.y, zv, acc[ 9]);
            acc[10] = fmaf(a2.z, zv, acc[10]);
            acc[11] = fmaf(a2.w, zv, acc[11]);
            acc[12] = fmaf(a3.x, zv, acc[12]);
            acc[13] = fmaf(a3.y, zv, acc[13]);
            acc[14] = fmaf(a3.z, zv, acc[14]);
            acc[15] = fmaf(a3.w, zv, acc[15]);

            a0 = b0; a1 = b1; a2 = b2; a3 = b3;
            b0 = n0; b1 = n1; b2 = n2; b3 = n3;
        }

        if (hk == 0) {
            #pragma unroll
            for (int j = 0; j < 16; ++j)
                Ls[(rh0 + j) * NT + lane] = acc[j] + c0v[rh0 + j];
        } else {
            #pragma unroll
            for (int j = 0; j < 16; ++j)
                Lp[(rh0 + j) * NT + lane] = acc[j];
        }
    }
    __syncthreads();

    // ---- softmax over r per (h,p); folds split-K reduce. waves 0..7 ----
    if (tid < 512) {
        const int h = tid >> 6;                // == w for tid<512
        float vals[R_];
        float m = -1e30f;
        #pragma unroll
        for (int r = 0; r < R_; ++r) {
            const int row = (r * NH_ + h) * NT + lane;
            vals[r] = Ls[row] + Lp[row];
            m = fmaxf(m, vals[r]);
        }
        float s = 0.f;
        #pragma unroll
        for (int r = 0; r < R_; ++r) { vals[r] = __expf(vals[r] - m); s += vals[r]; }
        const float inv = 1.f / s;
        #pragma unroll
        for (int r = 0; r < R_; ++r) Ls[(r * NH_ + h) * NT + lane] = vals[r] * inv;
    }
    __syncthreads();

    // ---- GEMM2: wave w -> c rows [16w, 16w+16), K = 128 ----
    {
        const int c0 = w << 4;
        const float* up = Uo + c0;             // row stride C_

        float4 a0 = LD4(up + 0),       a1 = LD4(up + 4),
               a2 = LD4(up + 8),       a3 = LD4(up + 12);
        float4 b0 = LD4(up + C_ + 0),  b1 = LD4(up + C_ + 4),
               b2 = LD4(up + C_ + 8),  b3 = LD4(up + C_ + 12);

        float acc[16];
        #pragma unroll
        for (int j = 0; j < 16; ++j) acc[j] = 0.f;

        #pragma unroll 2
        for (int rh = 0; rh < RH_; ++rh) {
            const float av = Ls[rh * NT + lane];
            const int rr = (rh + 2 < 128) ? rh + 2 : 127;
            const float4 n0 = LD4(up + (size_t)rr * C_ + 0);
            const float4 n1 = LD4(up + (size_t)rr * C_ + 4);
            const float4 n2 = LD4(up + (size_t)rr * C_ + 8);
            const float4 n3 = LD4(up + (size_t)rr * C_ + 12);

            acc[ 0] = fmaf(a0.x, av, acc[ 0]);
            acc[ 1] = fmaf(a0.y, av, acc[ 1]);
            acc[ 2] = fmaf(a0.z, av, acc[ 2]);
            acc[ 3] = fmaf(a0.w, av, acc[ 3]);
            acc[ 4] = fmaf(a1.x, av, acc[ 4]);
            acc[ 5] = fmaf(a1.y, av, acc[ 5]);
            acc[ 6] = fmaf(a1.z, av, acc[ 6]);
            acc[ 7] = fmaf(a1.w, av, acc[ 7]);
            acc[ 8] = fmaf(a2.x, av, acc[ 8]);
            acc[ 9] = fmaf(a2.y, av, acc[ 9]);
            acc[10] = fmaf(a2.z, av, acc[10]);
            acc[11] = fmaf(a2.w, av, acc[11]);
            acc[12] = fmaf(a3.x, av, acc[12]);
            acc[13] = fmaf(a3.y, av, acc[13]);
            acc[14] = fmaf(a3.z, av, acc[14]);
            acc[15] = fmaf(a3.w, av, acc[15]);

            a0 = b0; a1 = b1; a2 = b2; a3 = b3;
            b0 = n0; b1 = n1; b2 = n2; b3 = n3;
        }

        float* ob = out + ((size_t)b * C_ + c0) * XY_ + xy0;
        #pragma unroll
        for (int j = 0; j < 16; ++j)
            ob[(size_t)j * XY_ + lane] = acc[j] + bm[c0 + j];
    }
}

// ---------------------------------------------------------------------------
extern "C" void kernel_launch(void* const* d_in, const int* in_sizes, int n_in,
                              void* d_out, int out_size, void* d_ws, size_t ws_size,
                              hipStream_t stream)
{
    const float* z    = (const float*)d_in[0];
    const float* rims = (const float*)d_in[1];
    const float* Wk   = (const float*)d_in[2];
    const float* bk   = (const float*)d_in[3];
    const float* Wv   = (const float*)d_in[4];
    const float* bv   = (const float*)d_in[5];
    const float* Wq   = (const float*)d_in[6];
    const float* bq   = (const float*)d_in[7];
    const float* Wm   = (const float*)d_in[8];
    const float* bm   = (const float*)d_in[9];
    float* out = (float*)d_out;

    // ws layout: WLt (C_*RH_) | Uo (RH_*C_) | c0 (RH_)  -> ~257 KB
    float* WLt = (float*)d_ws;
    float* Uo  = WLt + C_ * RH_;
    float* c0o = Uo + RH_ * C_;

    rims_precompute<<<2 * RH_, 256, 0, stream>>>(rims, Wk, bk, Wv, bv, Wq, bq, Wm,
                                                 WLt, Uo, c0o);
    rims_main<<<(B_ * XY_) / NT, 1024, 0, stream>>>(z, WLt, Uo, c0o, bm, out);
}

// Round 8
// 51.294 us; speedup vs baseline: 1.2804x; 1.2804x over previous
//
#include <hip/hip_runtime.h>
#include <cstdint>
#include <cstddef>

// Dims (fixed by the reference)
#define R_   16
#define NH_  8
#define D_   32
#define C_   256
#define B_   16
#define XY_  1024      // 32*32
#define RH_  128       // R_*NH_
#define KD_  4096      // R_*NH_*D_
#define NT   64        // positions per block (lane = position)

#define LD4(p) (*reinterpret_cast<const float4*>(p))

// ---------------------------------------------------------------------------
// Precompute, 2x parallel (256 blocks): bid = rh*2 + half.
//   half 0: k[d] = Wk[r,h*D+d,:]·rims[r,:]+bk  ->  WLt[c][rh], c0[rh]
//   half 1: v[d] = Wv[...]·rims+bv             ->  Uo[rh][c]
// ---------------------------------------------------------------------------
__global__ __launch_bounds__(256)
void rims_precompute(const float* __restrict__ rims,
                     const float* __restrict__ Wk,
                     const float* __restrict__ bk,
                     const float* __restrict__ Wv,
                     const float* __restrict__ bv,
                     const float* __restrict__ Wq,
                     const float* __restrict__ bq,
                     const float* __restrict__ Wm,
                     float* __restrict__ WLt,
                     float* __restrict__ Uo,
                     float* __restrict__ c0o)
{
    const int bid  = blockIdx.x;       // 0..255
    const int rh   = bid >> 1;         // 0..127
    const int half = bid & 1;          // 0: k/WLt, 1: v/Uo
    const int r    = rh >> 3;
    const int h    = rh & 7;
    const int tid  = threadIdx.x;

    __shared__ float kv[D_];

    {
        const int d    = tid >> 3;     // 0..31
        const int part = tid & 7;      // 0..7
        const float* Wsrc = (half ? Wv : Wk)
                          + ((size_t)r * 256 + h * D_ + d) * C_ + part * 32;
        const float* rr   = rims + r * C_ + part * 32;
        float a0 = 0.f, a1 = 0.f, a2 = 0.f, a3 = 0.f;
        #pragma unroll
        for (int j = 0; j < 8; ++j) {
            const float4 wv4 = LD4(Wsrc + j * 4);
            const float4 xv4 = LD4(rr + j * 4);
            a0 = fmaf(wv4.x, xv4.x, a0); a1 = fmaf(wv4.y, xv4.y, a1);
            a2 = fmaf(wv4.z, xv4.z, a2); a3 = fmaf(wv4.w, xv4.w, a3);
        }
        float acc = (a0 + a1) + (a2 + a3);
        acc += __shfl_xor(acc, 1);
        acc += __shfl_xor(acc, 2);
        acc += __shfl_xor(acc, 4);
        if (part == 0)
            kv[d] = acc + (half ? bv : bk)[r * 256 + h * D_ + d];
    }
    __syncthreads();

    const int c = tid;                 // 0..255
    if (half == 0) {
        float wl = 0.f;
        const float* wqp = Wq + (size_t)rh * D_ * C_ + c;
        #pragma unroll
        for (int d = 0; d < D_; ++d)
            wl = fmaf(kv[d], wqp[(size_t)d * C_], wl);
        WLt[c * RH_ + rh] = wl;        // [c][rh]

        if (tid < D_) {
            float s = kv[tid] * bq[rh * D_ + tid];
            s += __shfl_xor(s, 1);  s += __shfl_xor(s, 2);  s += __shfl_xor(s, 4);
            s += __shfl_xor(s, 8);  s += __shfl_xor(s, 16);
            if (tid == 0) c0o[rh] = s;
        }
    } else {
        float uu = 0.f;
        const float* wmp = Wm + (size_t)c * KD_ + rh * D_;
        #pragma unroll
        for (int d4 = 0; d4 < D_; d4 += 4) {
            const float4 m4 = LD4(wmp + d4);
            uu = fmaf(kv[d4 + 0], m4.x, uu);
            uu = fmaf(kv[d4 + 1], m4.y, uu);
            uu = fmaf(kv[d4 + 2], m4.z, uu);
            uu = fmaf(kv[d4 + 3], m4.w, uu);
        }
        Uo[rh * C_ + c] = uu;          // [rh][c]
    }
}

// ---------------------------------------------------------------------------
// Fused main: 256 blocks (1/CU) x 1024 threads (16 waves). lane = position.
//   GEMM1 4-way split-K, z in REGISTERS:
//     wave w: rh rows [(w>>2)*32, +32), K-quarter kq = w&3 (c in [64kq, +64)).
//     lane loads its 64 z values straight from global (coalesced 256 B/instr;
//     4x L2 re-read of z, HBM unique traffic unchanged). Fully unrolled
//     64x32 FMA loop: ZERO LDS reads, 128 B/step uniform weights (plain
//     indexed reads -> s_load; NO manual prefetch, SMEM returns unordered).
//   Partials -> P[4] in LDS; softmax folds the 4-way reduce + c0.
//   GEMM2: wave w owns 16 c rows, K=128 (FMA-bound already).
// LDS = 128 KB (4 partial buffers). Only 2 barriers total.
// ---------------------------------------------------------------------------
__global__ __launch_bounds__(1024, 4)
void rims_main(const float* __restrict__ z,
               const float* __restrict__ WLt,
               const float* __restrict__ Uo,
               const float* __restrict__ c0v,
               const float* __restrict__ bm,
               float* __restrict__ out)
{
    __shared__ __align__(16) float P[4][RH_ * NT];   // 4 x 32 KB partials

    const int tid  = threadIdx.x;
    const int lane = tid & 63;
    const int w    = __builtin_amdgcn_readfirstlane(tid >> 6);  // 0..15
    const int kq   = w & 3;            // K-quarter
    const int rh0  = (w >> 2) << 5;    // 0,32,64,96
    const int b    = blockIdx.x >> 4;
    const int xy0  = (blockIdx.x & 15) * NT;

    // ---- load this wave's 64 z values into registers (coalesced) ----
    float zq[64];
    {
        const float* zg = z + ((size_t)b * C_ + kq * 64) * XY_ + xy0 + lane;
        #pragma unroll
        for (int j = 0; j < 64; ++j)
            zq[j] = zg[(size_t)j * XY_];
    }

    // ---- GEMM1: 32 rh rows x 64 k, zero LDS reads ----
    {
        float acc[32];
        #pragma unroll
        for (int m = 0; m < 32; ++m) acc[m] = 0.f;

        const float* wp = WLt + (size_t)(kq * 64) * RH_ + rh0;  // uniform
        #pragma unroll
        for (int j = 0; j < 64; ++j) {
            const float zv = zq[j];
            #pragma unroll
            for (int m = 0; m < 32; ++m)
                acc[m] = fmaf(wp[j * RH_ + m], zv, acc[m]);
        }

        float* pp = &P[kq][rh0 * NT + lane];
        #pragma unroll
        for (int m = 0; m < 32; ++m)
            pp[m * NT] = acc[m];
    }
    __syncthreads();

    // ---- softmax over r per (h,p); folds 4-way split-K reduce + c0 ----
    if (tid < 512) {
        const int h = tid >> 6;                // 0..7
        float vals[R_];
        float mx = -1e30f;
        #pragma unroll
        for (int r = 0; r < R_; ++r) {
            const int row = r * NH_ + h;
            const int idx = row * NT + lane;
            vals[r] = ((P[0][idx] + P[1][idx]) + (P[2][idx] + P[3][idx]))
                    + c0v[row];
            mx = fmaxf(mx, vals[r]);
        }
        float s = 0.f;
        #pragma unroll
        for (int r = 0; r < R_; ++r) { vals[r] = __expf(vals[r] - mx); s += vals[r]; }
        const float inv = 1.f / s;
        #pragma unroll
        for (int r = 0; r < R_; ++r)
            P[0][(r * NH_ + h) * NT + lane] = vals[r] * inv;
    }
    __syncthreads();

    // ---- GEMM2: wave w -> c rows [16w, 16w+16), K = 128 ----
    {
        const int c0 = w << 4;
        float acc2[16];
        #pragma unroll
        for (int j = 0; j < 16; ++j) acc2[j] = 0.f;
        const float* up = Uo + c0;             // uniform; row stride C_

        #pragma unroll 4
        for (int rh = 0; rh < RH_; ++rh) {
            const float av = P[0][rh * NT + lane];
            #pragma unroll
            for (int j = 0; j < 16; ++j)
                acc2[j] = fmaf(up[rh * C_ + j], av, acc2[j]);
        }

        float* ob = out + ((size_t)b * C_ + c0) * XY_ + xy0;
        #pragma unroll
        for (int j = 0; j < 16; ++j)
            ob[(size_t)j * XY_ + lane] = acc2[j] + bm[c0 + j];
    }
}

// ---------------------------------------------------------------------------
extern "C" void kernel_launch(void* const* d_in, const int* in_sizes, int n_in,
                              void* d_out, int out_size, void* d_ws, size_t ws_size,
                              hipStream_t stream)
{
    const float* z    = (const float*)d_in[0];
    const float* rims = (const float*)d_in[1];
    const float* Wk   = (const float*)d_in[2];
    const float* bk   = (const float*)d_in[3];
    const float* Wv   = (const float*)d_in[4];
    const float* bv   = (const float*)d_in[5];
    const float* Wq   = (const float*)d_in[6];
    const float* bq   = (const float*)d_in[7];
    const float* Wm   = (const float*)d_in[8];
    const float* bm   = (const float*)d_in[9];
    float* out = (float*)d_out;

    // ws layout: WLt (C_*RH_) | Uo (RH_*C_) | c0 (RH_)  -> ~257 KB
    float* WLt = (float*)d_ws;
    float* Uo  = WLt + C_ * RH_;
    float* c0o = Uo + RH_ * C_;

    rims_precompute<<<2 * RH_, 256, 0, stream>>>(rims, Wk, bk, Wv, bv, Wq, bq, Wm,
                                                 WLt, Uo, c0o);
    rims_main<<<(B_ * XY_) / NT, 1024, 0, stream>>>(z, WLt, Uo, c0o, bm, out);
}